// Round 1
// baseline (1160.865 us; speedup 1.0000x reference)
//
#include <hip/hip_runtime.h>
#include <hip/hip_bf16.h>
#include <math.h>

#define B_ 8
#define N_ 900
#define D_ 256
#define S_ 21760
#define H_ 8
#define DH 32
#define FF_ 2048
#define NROWS (B_*N_)   // 7200

// ---------------------------------------------------------------- RoPE
// out = rope(tgt + query_pos, boxes); dims 0..251 rotated, 252..255 pass.
__global__ __launch_bounds__(128) void rope_kernel(
    const float* __restrict__ tgt, const float* __restrict__ qpos,
    const float* __restrict__ boxes, float* __restrict__ out)
{
  int row = blockIdx.x;           // b*N+n
  int tid = threadIdx.x;          // pair index: dims 2*tid, 2*tid+1
  const float* x = tgt  + (size_t)row * D_;
  const float* p = qpos + (size_t)row * D_;
  float a0 = x[2*tid]   + p[2*tid];
  float a1 = x[2*tid+1] + p[2*tid+1];
  float o0 = a0, o1 = a1;
  if (tid < 126) {
    int band = tid / 42;          // 0:cx 1:cy 2:cx*cy
    int fi   = tid - band * 42;
    float freq = powf(10000.0f, -(float)fi / 42.0f);
    float cx = boxes[(size_t)row*4 + 0];
    float cy = boxes[(size_t)row*4 + 1];
    float v  = (band == 0) ? cx : (band == 1 ? cy : cx * cy);
    if (band == 2) freq *= 0.1f;
    float ang = v * freq;
    float c = cosf(ang), s = sinf(ang);
    o0 = a0 * c - a1 * s;         // rotate_half: out[2i]   = a0*c - a1*s
    o1 = a1 * c + a0 * s;         //              out[2i+1] = a1*c + a0*s
  }
  out[(size_t)row*D_ + 2*tid]   = o0;
  out[(size_t)row*D_ + 2*tid+1] = o1;
}

// ---------------------------------------------------------------- GEMM
// C[M,N] = A[M,K] @ W[K,N] + bias ; optional relu, optional bf16 out.
// 64x64 tile, BK=16, 256 threads, 4x4 micro-tile.
template<bool RELU, typename OT>
__global__ __launch_bounds__(256) void gemm_kernel(
    const float* __restrict__ A, const float* __restrict__ W,
    const float* __restrict__ bias, OT* __restrict__ C,
    int M, int N, int K)
{
  __shared__ float As[16][68];   // transposed [k][m], stride 68 -> 16B-aligned rows
  __shared__ float Bs[16][64];   // [k][n]
  int tid = threadIdx.x;
  int tx = tid & 15, ty = tid >> 4;
  int m0 = blockIdx.y * 64, n0 = blockIdx.x * 64;
  int arow = tid >> 2, ac4 = (tid & 3) * 4;
  int brow = tid >> 4, bc4 = (tid & 15) * 4;
  float acc[4][4] = {};
  for (int k0 = 0; k0 < K; k0 += 16) {
    float4 av = make_float4(0.f,0.f,0.f,0.f);
    if (m0 + arow < M) av = *(const float4*)&A[(size_t)(m0+arow)*K + k0 + ac4];
    As[ac4+0][arow] = av.x; As[ac4+1][arow] = av.y;
    As[ac4+2][arow] = av.z; As[ac4+3][arow] = av.w;
    float4 bv = *(const float4*)&W[(size_t)(k0+brow)*N + n0 + bc4];
    *(float4*)&Bs[brow][bc4] = bv;
    __syncthreads();
    #pragma unroll
    for (int kk = 0; kk < 16; ++kk) {
      float4 a4 = *(const float4*)&As[kk][ty*4];
      float4 b4 = *(const float4*)&Bs[kk][tx*4];
      float a[4] = {a4.x, a4.y, a4.z, a4.w};
      float b[4] = {b4.x, b4.y, b4.z, b4.w};
      #pragma unroll
      for (int i = 0; i < 4; ++i)
        #pragma unroll
        for (int j = 0; j < 4; ++j) acc[i][j] += a[i] * b[j];
    }
    __syncthreads();
  }
  #pragma unroll
  for (int i = 0; i < 4; ++i) {
    int r = m0 + ty*4 + i;
    if (r >= M) break;
    #pragma unroll
    for (int j = 0; j < 4; ++j) {
      int c = n0 + tx*4 + j;
      float v = acc[i][j] + bias[c];
      if (RELU) v = fmaxf(v, 0.0f);
      if constexpr (__hip_internal::is_same<OT, __hip_bfloat16>::value)
        C[(size_t)r*N + c] = __float2bfloat16(v);
      else
        C[(size_t)r*N + c] = v;
    }
  }
}

// ---------------------------------------------------------------- self-attention
// one thread per q-row; online softmax; K/V tiles of 64 rows staged in LDS.
// grid (4, B*H), block 256. Layouts: (B,N,H*DH).
__global__ __launch_bounds__(256) void attn_kernel(
    const float* __restrict__ Q, const float* __restrict__ Kg,
    const float* __restrict__ Vg, float* __restrict__ O)
{
  __shared__ float ks[64][32];
  __shared__ float vs[64][32];
  int tid = threadIdx.x;
  int bh = blockIdx.y; int b = bh >> 3, h = bh & 7;
  int n = blockIdx.x * 256 + tid;
  bool active = n < N_;
  const float scale = 0.17677669529663687f;  // 32^-0.5
  float q[DH];
  if (active) {
    const float* qp = Q + ((size_t)(b*N_ + n))*D_ + h*DH;
    #pragma unroll
    for (int d = 0; d < DH; d += 4) {
      float4 t = *(const float4*)&qp[d];
      q[d] = t.x; q[d+1] = t.y; q[d+2] = t.z; q[d+3] = t.w;
    }
  }
  float m = -1e30f, l = 0.0f, acc[DH] = {};
  for (int kt = 0; kt < N_; kt += 64) {
    int jmax = min(64, N_ - kt);
    #pragma unroll
    for (int i = 0; i < 2; ++i) {
      int e4 = i*256 + tid;
      int r = e4 >> 3, c4 = (e4 & 7) * 4;
      int kr = kt + r;
      float4 kv = make_float4(0.f,0.f,0.f,0.f), vv = kv;
      if (kr < N_) {
        size_t base = ((size_t)(b*N_ + kr))*D_ + h*DH + c4;
        kv = *(const float4*)&Kg[base];
        vv = *(const float4*)&Vg[base];
      }
      *(float4*)&ks[r][c4] = kv;
      *(float4*)&vs[r][c4] = vv;
    }
    __syncthreads();
    if (active) {
      for (int j = 0; j < jmax; ++j) {
        float s = 0.f;
        #pragma unroll
        for (int d4 = 0; d4 < DH; d4 += 4) {
          float4 k4 = *(const float4*)&ks[j][d4];
          s += q[d4]*k4.x + q[d4+1]*k4.y + q[d4+2]*k4.z + q[d4+3]*k4.w;
        }
        s *= scale;
        if (s <= m) {
          float p = __expf(s - m);
          l += p;
          #pragma unroll
          for (int d4 = 0; d4 < DH; d4 += 4) {
            float4 v4 = *(const float4*)&vs[j][d4];
            acc[d4]   += p*v4.x; acc[d4+1] += p*v4.y;
            acc[d4+2] += p*v4.z; acc[d4+3] += p*v4.w;
          }
        } else {
          float corr = __expf(m - s);
          m = s;
          l = l*corr + 1.0f;
          #pragma unroll
          for (int d4 = 0; d4 < DH; d4 += 4) {
            float4 v4 = *(const float4*)&vs[j][d4];
            acc[d4]   = acc[d4]  *corr + v4.x; acc[d4+1] = acc[d4+1]*corr + v4.y;
            acc[d4+2] = acc[d4+2]*corr + v4.z; acc[d4+3] = acc[d4+3]*corr + v4.w;
          }
        }
      }
    }
    __syncthreads();
  }
  if (active) {
    float inv = 1.0f / l;
    float* op = O + ((size_t)(b*N_ + n))*D_ + h*DH;
    #pragma unroll
    for (int d = 0; d < DH; ++d) op[d] = acc[d] * inv;
  }
}

// ---------------------------------------------------------------- add + LayerNorm
// out = LN(X + Y) * g + beta.  One block per row. in-place (out==X) safe.
__global__ __launch_bounds__(256) void add_ln_kernel(
    const float* __restrict__ X, const float* __restrict__ Y,
    const float* __restrict__ g, const float* __restrict__ beta,
    float* __restrict__ out)
{
  int row = blockIdx.x, tid = threadIdx.x;
  float v = X[(size_t)row*D_ + tid] + Y[(size_t)row*D_ + tid];
  float s = v, s2 = v*v;
  #pragma unroll
  for (int off = 32; off; off >>= 1) {
    s  += __shfl_down(s,  off, 64);
    s2 += __shfl_down(s2, off, 64);
  }
  __shared__ float red[8];
  int wid = tid >> 6, lane = tid & 63;
  if (lane == 0) { red[wid] = s; red[wid+4] = s2; }
  __syncthreads();
  if (tid == 0) {
    float ts  = red[0]+red[1]+red[2]+red[3];
    float ts2 = red[4]+red[5]+red[6]+red[7];
    float mu  = ts * (1.0f/D_);
    float var = ts2 * (1.0f/D_) - mu*mu;
    red[0] = mu;
    red[1] = rsqrtf(fmaxf(var, 0.0f) + 1e-5f);
  }
  __syncthreads();
  float mu = red[0], r = red[1];
  out[(size_t)row*D_ + tid] = (v - mu)*r*g[tid] + beta[tid];
}

// ---------------------------------------------------------------- elementwise add
__global__ __launch_bounds__(256) void add_kernel(
    const float* __restrict__ a, const float* __restrict__ b,
    float* __restrict__ c, int n)
{
  int i = blockIdx.x * 256 + threadIdx.x;
  if (i < n) c[i] = a[i] + b[i];
}

// ---------------------------------------------------------------- deformable sampling
// per (b,n): aw softmax (8 groups of 16), loc = refp + off/norm, then for each
// (h,d) thread: sum over l,p of aw * bilinear(value_level_l, loc).
__global__ __launch_bounds__(256) void sample_kernel(
    const __hip_bfloat16* __restrict__ V, const float* __restrict__ offp,
    const float* __restrict__ awl, const float* __restrict__ refp,
    float* __restrict__ out)
{
  int row = blockIdx.x;          // b*N+n
  int b = row / N_;
  int tid = threadIdx.x;
  __shared__ float s_aw[128];    // (h, l*4+p)
  __shared__ float s_loc[256];   // (h, l, p, axis)
  if (tid < 128) s_aw[tid] = awl[(size_t)row*128 + tid];
  {
    int rem = tid & 31;
    int l = rem >> 3, ax = rem & 1;
    const float norms[4] = {128.f, 64.f, 32.f, 16.f};
    float off = offp[(size_t)row*256 + tid];
    float rp  = refp[((size_t)row*4 + l)*2 + ax];
    s_loc[tid] = rp + off / norms[l];
  }
  __syncthreads();
  if (tid < 8) {
    float mx = -1e30f;
    for (int j = 0; j < 16; ++j) mx = fmaxf(mx, s_aw[tid*16+j]);
    float sum = 0.f;
    for (int j = 0; j < 16; ++j) sum += __expf(s_aw[tid*16+j] - mx);
    float inv = 1.0f / sum;
    for (int j = 0; j < 16; ++j) s_aw[tid*16+j] = __expf(s_aw[tid*16+j] - mx) * inv;
  }
  __syncthreads();
  int h = tid >> 5, d = tid & 31;
  const int dims[4]   = {128, 64, 32, 16};
  const int starts[4] = {0, 16384, 20480, 21504};
  const __hip_bfloat16* Vb = V + ((size_t)b*S_)*D_ + h*DH + d;
  float acc = 0.f;
  #pragma unroll
  for (int l = 0; l < 4; ++l) {
    int Wl = dims[l], st = starts[l];
    #pragma unroll
    for (int p = 0; p < 4; ++p) {
      float lx = s_loc[h*32 + l*8 + p*2 + 0];
      float ly = s_loc[h*32 + l*8 + p*2 + 1];
      float x = lx * Wl - 0.5f, y = ly * Wl - 0.5f;   // Hl == Wl
      float x0f = floorf(x), y0f = floorf(y);
      float fx = x - x0f, fy = y - y0f;
      int x0 = (int)x0f, y0 = (int)y0f;
      float v = 0.f;
      #pragma unroll
      for (int ty = 0; ty < 2; ++ty) {
        int yi = y0 + ty;
        float wy = ty ? fy : (1.f - fy);
        if (yi < 0 || yi >= Wl) continue;
        #pragma unroll
        for (int txi = 0; txi < 2; ++txi) {
          int xi = x0 + txi;
          float wx = txi ? fx : (1.f - fx);
          if (xi < 0 || xi >= Wl) continue;
          v += wy * wx * __bfloat162float(Vb[(size_t)(st + yi*Wl + xi) * D_]);
        }
      }
      acc += s_aw[h*16 + l*4 + p] * v;
    }
  }
  out[(size_t)row*D_ + tid] = acc;
}

// ================================================================ launch
extern "C" void kernel_launch(void* const* d_in, const int* in_sizes, int n_in,
                              void* d_out, int out_size, void* d_ws, size_t ws_size,
                              hipStream_t stream)
{
  const float* tgt    = (const float*)d_in[0];
  const float* memory = (const float*)d_in[1];
  const float* qpos   = (const float*)d_in[2];
  const float* boxes  = (const float*)d_in[3];
  const float* refp   = (const float*)d_in[4];
  const float* wq = (const float*)d_in[5];   const float* bq = (const float*)d_in[6];
  const float* wk = (const float*)d_in[7];   const float* bk = (const float*)d_in[8];
  const float* wv = (const float*)d_in[9];   const float* bv = (const float*)d_in[10];
  const float* sa_wo = (const float*)d_in[11]; const float* sa_bo = (const float*)d_in[12];
  const float* n1g = (const float*)d_in[13]; const float* n1b = (const float*)d_in[14];
  const float* off_w = (const float*)d_in[15]; const float* off_b = (const float*)d_in[16];
  const float* aw_w  = (const float*)d_in[17]; const float* aw_b  = (const float*)d_in[18];
  const float* val_w = (const float*)d_in[19]; const float* val_b = (const float*)d_in[20];
  const float* co_w  = (const float*)d_in[21]; const float* co_b  = (const float*)d_in[22];
  const float* n2g = (const float*)d_in[23]; const float* n2b = (const float*)d_in[24];
  const float* ff1_w = (const float*)d_in[25]; const float* ff1_b = (const float*)d_in[26];
  const float* ff2_w = (const float*)d_in[27]; const float* ff2_b = (const float*)d_in[28];
  const float* n3g = (const float*)d_in[29]; const float* n3b = (const float*)d_in[30];

  // ---- workspace layout (phase-based reuse). total = 89,128,960 + 7*7,372,800
  //      = 140,738,560 bytes.
  char* ws = (char*)d_ws;
  size_t NE = (size_t)NROWS * D_;                 // 1,843,200
  __hip_bfloat16* Vv = (__hip_bfloat16*)ws;       // value, bf16 (B*S*D) — dead after sampling
  float* FFM = (float*)ws;                        // ffn hidden overlays value region
  size_t p = (size_t)B_ * S_ * D_ * sizeof(__hip_bfloat16);   // 89,128,960
  float* A  = (float*)(ws + p); p += NE*4;        // xrope / q2
  float* Qb = (float*)(ws + p); p += NE*4;        // qh / off
  float* Kb = (float*)(ws + p); p += NE*4;        // kh / aw-logits
  float* Vh = (float*)(ws + p); p += NE*4;        // vh
  float* S1 = (float*)(ws + p); p += NE*4;        // sa out / ca out
  float* S2 = (float*)(ws + p); p += NE*4;        // proj out
  float* T1 = (float*)(ws + p); p += NE*4;        // tgt1 / tgt2
  float* out = (float*)d_out;
  (void)ws_size; (void)in_sizes; (void)n_in; (void)out_size;

  dim3 g64(4, (NROWS + 63) / 64);

  // self-attention branch
  rope_kernel<<<NROWS, 128, 0, stream>>>(tgt, qpos, boxes, A);
  gemm_kernel<false,float><<<g64, 256, 0, stream>>>(A,   wq, bq, Qb, NROWS, 256, 256);
  gemm_kernel<false,float><<<g64, 256, 0, stream>>>(A,   wk, bk, Kb, NROWS, 256, 256);
  gemm_kernel<false,float><<<g64, 256, 0, stream>>>(tgt, wv, bv, Vh, NROWS, 256, 256);
  attn_kernel<<<dim3(4, B_*H_), 256, 0, stream>>>(Qb, Kb, Vh, S1);
  gemm_kernel<false,float><<<g64, 256, 0, stream>>>(S1, sa_wo, sa_bo, S2, NROWS, 256, 256);
  add_ln_kernel<<<NROWS, 256, 0, stream>>>(tgt, S2, n1g, n1b, T1);

  // cross-attention branch
  gemm_kernel<false,__hip_bfloat16><<<dim3(4, (B_*S_ + 63)/64), 256, 0, stream>>>(
      memory, val_w, val_b, Vv, B_*S_, 256, 256);
  add_kernel<<<(int)((NE + 255)/256), 256, 0, stream>>>(T1, qpos, A, (int)NE);
  gemm_kernel<false,float><<<g64, 256, 0, stream>>>(A, off_w, off_b, Qb, NROWS, 256, 256);
  gemm_kernel<false,float><<<dim3(2, (NROWS + 63)/64), 256, 0, stream>>>(
      A, aw_w, aw_b, Kb, NROWS, 128, 256);
  sample_kernel<<<NROWS, 256, 0, stream>>>(Vv, Qb, Kb, refp, S1);
  gemm_kernel<false,float><<<g64, 256, 0, stream>>>(S1, co_w, co_b, S2, NROWS, 256, 256);
  add_ln_kernel<<<NROWS, 256, 0, stream>>>(T1, S2, n2g, n2b, T1);

  // ffn
  gemm_kernel<true,float><<<dim3(FF_/64, (NROWS + 63)/64), 256, 0, stream>>>(
      T1, ff1_w, ff1_b, FFM, NROWS, FF_, 256);
  gemm_kernel<false,float><<<g64, 256, 0, stream>>>(FFM, ff2_w, ff2_b, S2, NROWS, 256, FF_);
  add_ln_kernel<<<NROWS, 256, 0, stream>>>(T1, S2, n3g, n3b, out);
}

// Round 2
// 895.769 us; speedup vs baseline: 1.2959x; 1.2959x over previous
//
#include <hip/hip_runtime.h>
#include <hip/hip_bf16.h>
#include <math.h>

#define B_ 8
#define N_ 900
#define D_ 256
#define S_ 21760
#define H_ 8
#define DH 32
#define FF_ 2048
#define NROWS (B_*N_)   // 7200

typedef __attribute__((ext_vector_type(8))) short bf16x8;
typedef __attribute__((ext_vector_type(4))) float f32x4;

static __device__ inline short f2bf_s(float x) {
  __hip_bfloat16 h = __float2bfloat16(x);
  return *reinterpret_cast<short*>(&h);
}

// ---------------------------------------------------------------- RoPE
__global__ __launch_bounds__(128) void rope_kernel(
    const float* __restrict__ tgt, const float* __restrict__ qpos,
    const float* __restrict__ boxes, float* __restrict__ out)
{
  int row = blockIdx.x;
  int tid = threadIdx.x;
  const float* x = tgt  + (size_t)row * D_;
  const float* p = qpos + (size_t)row * D_;
  float a0 = x[2*tid]   + p[2*tid];
  float a1 = x[2*tid+1] + p[2*tid+1];
  float o0 = a0, o1 = a1;
  if (tid < 126) {
    int band = tid / 42;
    int fi   = tid - band * 42;
    float freq = powf(10000.0f, -(float)fi / 42.0f);
    float cx = boxes[(size_t)row*4 + 0];
    float cy = boxes[(size_t)row*4 + 1];
    float v  = (band == 0) ? cx : (band == 1 ? cy : cx * cy);
    if (band == 2) freq *= 0.1f;
    float ang = v * freq;
    float c = cosf(ang), s = sinf(ang);
    o0 = a0 * c - a1 * s;
    o1 = a1 * c + a0 * s;
  }
  out[(size_t)row*D_ + 2*tid]   = o0;
  out[(size_t)row*D_ + 2*tid+1] = o1;
}

// ---------------------------------------------------------------- GEMM (fp32 VALU)
template<bool RELU, typename OT>
__global__ __launch_bounds__(256) void gemm_kernel(
    const float* __restrict__ A, const float* __restrict__ W,
    const float* __restrict__ bias, OT* __restrict__ C,
    int M, int N, int K)
{
  __shared__ float As[16][68];
  __shared__ float Bs[16][64];
  int tid = threadIdx.x;
  int tx = tid & 15, ty = tid >> 4;
  int m0 = blockIdx.y * 64, n0 = blockIdx.x * 64;
  int arow = tid >> 2, ac4 = (tid & 3) * 4;
  int brow = tid >> 4, bc4 = (tid & 15) * 4;
  float acc[4][4] = {};
  for (int k0 = 0; k0 < K; k0 += 16) {
    float4 av = make_float4(0.f,0.f,0.f,0.f);
    if (m0 + arow < M) av = *(const float4*)&A[(size_t)(m0+arow)*K + k0 + ac4];
    As[ac4+0][arow] = av.x; As[ac4+1][arow] = av.y;
    As[ac4+2][arow] = av.z; As[ac4+3][arow] = av.w;
    float4 bv = *(const float4*)&W[(size_t)(k0+brow)*N + n0 + bc4];
    *(float4*)&Bs[brow][bc4] = bv;
    __syncthreads();
    #pragma unroll
    for (int kk = 0; kk < 16; ++kk) {
      float4 a4 = *(const float4*)&As[kk][ty*4];
      float4 b4 = *(const float4*)&Bs[kk][tx*4];
      float a[4] = {a4.x, a4.y, a4.z, a4.w};
      float b[4] = {b4.x, b4.y, b4.z, b4.w};
      #pragma unroll
      for (int i = 0; i < 4; ++i)
        #pragma unroll
        for (int j = 0; j < 4; ++j) acc[i][j] += a[i] * b[j];
    }
    __syncthreads();
  }
  #pragma unroll
  for (int i = 0; i < 4; ++i) {
    int r = m0 + ty*4 + i;
    if (r >= M) break;
    #pragma unroll
    for (int j = 0; j < 4; ++j) {
      int c = n0 + tx*4 + j;
      float v = acc[i][j] + bias[c];
      if (RELU) v = fmaxf(v, 0.0f);
      if constexpr (__hip_internal::is_same<OT, __hip_bfloat16>::value)
        C[(size_t)r*N + c] = __float2bfloat16(v);
      else
        C[(size_t)r*N + c] = v;
    }
  }
}

// ---- V-projection GEMM with transposed bf16 store: Vt[((b*8+h)*32+d)][n]
__global__ __launch_bounds__(256) void gemm_tv_kernel(
    const float* __restrict__ A, const float* __restrict__ W,
    const float* __restrict__ bias, __hip_bfloat16* __restrict__ Vt,
    int M, int N, int K)
{
  __shared__ float As[16][68];
  __shared__ float Bs[16][64];
  int tid = threadIdx.x;
  int tx = tid & 15, ty = tid >> 4;
  int m0 = blockIdx.y * 64, n0 = blockIdx.x * 64;
  int arow = tid >> 2, ac4 = (tid & 3) * 4;
  int brow = tid >> 4, bc4 = (tid & 15) * 4;
  float acc[4][4] = {};
  for (int k0 = 0; k0 < K; k0 += 16) {
    float4 av = make_float4(0.f,0.f,0.f,0.f);
    if (m0 + arow < M) av = *(const float4*)&A[(size_t)(m0+arow)*K + k0 + ac4];
    As[ac4+0][arow] = av.x; As[ac4+1][arow] = av.y;
    As[ac4+2][arow] = av.z; As[ac4+3][arow] = av.w;
    float4 bv = *(const float4*)&W[(size_t)(k0+brow)*N + n0 + bc4];
    *(float4*)&Bs[brow][bc4] = bv;
    __syncthreads();
    #pragma unroll
    for (int kk = 0; kk < 16; ++kk) {
      float4 a4 = *(const float4*)&As[kk][ty*4];
      float4 b4 = *(const float4*)&Bs[kk][tx*4];
      float a[4] = {a4.x, a4.y, a4.z, a4.w};
      float b[4] = {b4.x, b4.y, b4.z, b4.w};
      #pragma unroll
      for (int i = 0; i < 4; ++i)
        #pragma unroll
        for (int j = 0; j < 4; ++j) acc[i][j] += a[i] * b[j];
    }
    __syncthreads();
  }
  #pragma unroll
  for (int i = 0; i < 4; ++i) {
    int r = m0 + ty*4 + i;
    if (r >= M) break;
    int bb = r / N_, nn = r - bb * N_;
    #pragma unroll
    for (int j = 0; j < 4; ++j) {
      int c = n0 + tx*4 + j;
      int hh = c >> 5, dd = c & 31;
      Vt[(size_t)((bb*H_ + hh)*DH + dd)*N_ + nn] = __float2bfloat16(acc[i][j] + bias[c]);
    }
  }
}

// ---------------------------------------------------------------- MFMA flash attention
// one wave per 16-query tile. Swapped QK^T: S^T = mfma(K_frag, Q_frag).
// Lane l (g=l>>4, r=l&15): holds S[q=q0+r][key=kt+4g+reg] (+16 from 2nd mfma).
// P lands directly in PV B-fragment layout (k = 4g+(j&3)+16*(j>>2)).
__global__ __launch_bounds__(64) void mfma_attn_kernel(
    const __hip_bfloat16* __restrict__ Q,   // (B,N,256) bf16
    const __hip_bfloat16* __restrict__ K,   // (B,N,256) bf16
    const __hip_bfloat16* __restrict__ Vt,  // [(b*8+h)*32+d][900] bf16
    float* __restrict__ O)                  // (B,N,256) fp32
{
  const int NQT = 57;                       // ceil(900/16)
  int wid = blockIdx.x;
  int qt = wid % NQT, bh = wid / NQT;
  int b = bh >> 3, h = bh & 7;
  int lane = threadIdx.x;
  int g = lane >> 4, r = lane & 15;
  int q0 = qt * 16;
  const float scale = 0.17677669529663687f; // 32^-0.5

  union U { bf16x8 v; short s[8]; unsigned long long u64[2]; };

  // Q fragment (B operand): lane needs Q[q0+r][4g..4g+3, 16+4g..16+4g+3]
  U qf;
  {
    int qrow = min(q0 + r, N_ - 1);
    const __hip_bfloat16* qp = Q + ((size_t)(b*N_ + qrow))*D_ + h*DH;
    qf.u64[0] = *(const unsigned long long*)(qp + 4*g);
    qf.u64[1] = *(const unsigned long long*)(qp + 16 + 4*g);
  }

  f32x4 oacc0 = {0.f,0.f,0.f,0.f};          // dh 0..15
  f32x4 oacc1 = {0.f,0.f,0.f,0.f};          // dh 16..31
  float m = -1e30f, l = 0.0f;
  const f32x4 zero = {0.f,0.f,0.f,0.f};

  const __hip_bfloat16* vbase0 = Vt + (size_t)(bh*DH + r) * N_;         // dh half 0
  const __hip_bfloat16* vbase1 = Vt + (size_t)(bh*DH + 16 + r) * N_;    // dh half 1

  for (int kt = 0; kt < N_; kt += 32) {
    // K fragments (A operand): lane needs K[kt+t*16+r][4g.., 16+4g..]
    U kf0, kf1;
    {
      int kr0 = min(kt + r, N_ - 1);
      int kr1 = min(kt + 16 + r, N_ - 1);
      const __hip_bfloat16* kp0 = K + ((size_t)(b*N_ + kr0))*D_ + h*DH;
      const __hip_bfloat16* kp1 = K + ((size_t)(b*N_ + kr1))*D_ + h*DH;
      kf0.u64[0] = *(const unsigned long long*)(kp0 + 4*g);
      kf0.u64[1] = *(const unsigned long long*)(kp0 + 16 + 4*g);
      kf1.u64[0] = *(const unsigned long long*)(kp1 + 4*g);
      kf1.u64[1] = *(const unsigned long long*)(kp1 + 16 + 4*g);
    }
    f32x4 s0 = __builtin_amdgcn_mfma_f32_16x16x32_bf16(kf0.v, qf.v, zero, 0, 0, 0);
    f32x4 s1 = __builtin_amdgcn_mfma_f32_16x16x32_bf16(kf1.v, qf.v, zero, 0, 0, 0);

    float sc[8];
    #pragma unroll
    for (int j = 0; j < 4; ++j) {
      sc[j]   = (kt + 4*g + j      < N_) ? s0[j] * scale : -1e30f;
      sc[4+j] = (kt + 16 + 4*g + j < N_) ? s1[j] * scale : -1e30f;
    }
    float mx = sc[0];
    #pragma unroll
    for (int j = 1; j < 8; ++j) mx = fmaxf(mx, sc[j]);
    mx = fmaxf(mx, __shfl_xor(mx, 16));
    mx = fmaxf(mx, __shfl_xor(mx, 32));

    float mnew = fmaxf(m, mx);
    float corr = __expf(m - mnew);
    float p[8], ps = 0.f;
    #pragma unroll
    for (int j = 0; j < 8; ++j) { p[j] = __expf(sc[j] - mnew); ps += p[j]; }
    ps += __shfl_xor(ps, 16);
    ps += __shfl_xor(ps, 32);
    l = l * corr + ps;
    m = mnew;
    #pragma unroll
    for (int j = 0; j < 4; ++j) { oacc0[j] *= corr; oacc1[j] *= corr; }

    U pf;
    #pragma unroll
    for (int j = 0; j < 8; ++j) pf.s[j] = f2bf_s(p[j]);

    // V^T fragments (A operand): lane needs Vt[dh0+r][kt + 4g+(j&3)+16*(j>>2)]
    U vf0, vf1;
    vf0.u64[0] = *(const unsigned long long*)(vbase0 + kt + 4*g);
    vf0.u64[1] = *(const unsigned long long*)(vbase0 + kt + 16 + 4*g);
    vf1.u64[0] = *(const unsigned long long*)(vbase1 + kt + 4*g);
    vf1.u64[1] = *(const unsigned long long*)(vbase1 + kt + 16 + 4*g);

    oacc0 = __builtin_amdgcn_mfma_f32_16x16x32_bf16(vf0.v, pf.v, oacc0, 0, 0, 0);
    oacc1 = __builtin_amdgcn_mfma_f32_16x16x32_bf16(vf1.v, pf.v, oacc1, 0, 0, 0);
  }

  if (q0 + r < N_) {
    float inv = 1.0f / l;
    float* op = O + ((size_t)(b*N_ + q0 + r))*D_ + h*DH;
    #pragma unroll
    for (int j = 0; j < 4; ++j) {
      op[4*g + j]      = oacc0[j] * inv;
      op[16 + 4*g + j] = oacc1[j] * inv;
    }
  }
}

// ---------------------------------------------------------------- add + LayerNorm
__global__ __launch_bounds__(256) void add_ln_kernel(
    const float* __restrict__ X, const float* __restrict__ Y,
    const float* __restrict__ g, const float* __restrict__ beta,
    float* __restrict__ out)
{
  int row = blockIdx.x, tid = threadIdx.x;
  float v = X[(size_t)row*D_ + tid] + Y[(size_t)row*D_ + tid];
  float s = v, s2 = v*v;
  #pragma unroll
  for (int off = 32; off; off >>= 1) {
    s  += __shfl_down(s,  off, 64);
    s2 += __shfl_down(s2, off, 64);
  }
  __shared__ float red[8];
  int wid = tid >> 6, lane = tid & 63;
  if (lane == 0) { red[wid] = s; red[wid+4] = s2; }
  __syncthreads();
  if (tid == 0) {
    float ts  = red[0]+red[1]+red[2]+red[3];
    float ts2 = red[4]+red[5]+red[6]+red[7];
    float mu  = ts * (1.0f/D_);
    float var = ts2 * (1.0f/D_) - mu*mu;
    red[0] = mu;
    red[1] = rsqrtf(fmaxf(var, 0.0f) + 1e-5f);
  }
  __syncthreads();
  float mu = red[0], rr = red[1];
  out[(size_t)row*D_ + tid] = (v - mu)*rr*g[tid] + beta[tid];
}

// ---------------------------------------------------------------- elementwise add
__global__ __launch_bounds__(256) void add_kernel(
    const float* __restrict__ a, const float* __restrict__ b,
    float* __restrict__ c, int n)
{
  int i = blockIdx.x * 256 + threadIdx.x;
  if (i < n) c[i] = a[i] + b[i];
}

// ---------------------------------------------------------------- deformable sampling
__global__ __launch_bounds__(256) void sample_kernel(
    const __hip_bfloat16* __restrict__ V, const float* __restrict__ offp,
    const float* __restrict__ awl, const float* __restrict__ refp,
    float* __restrict__ out)
{
  int row = blockIdx.x;
  int b = row / N_;
  int tid = threadIdx.x;
  __shared__ float s_aw[128];
  __shared__ float s_loc[256];
  if (tid < 128) s_aw[tid] = awl[(size_t)row*128 + tid];
  {
    int rem = tid & 31;
    int l = rem >> 3, ax = rem & 1;
    const float norms[4] = {128.f, 64.f, 32.f, 16.f};
    float off = offp[(size_t)row*256 + tid];
    float rp  = refp[((size_t)row*4 + l)*2 + ax];
    s_loc[tid] = rp + off / norms[l];
  }
  __syncthreads();
  if (tid < 8) {
    float mx = -1e30f;
    for (int j = 0; j < 16; ++j) mx = fmaxf(mx, s_aw[tid*16+j]);
    float sum = 0.f;
    for (int j = 0; j < 16; ++j) sum += __expf(s_aw[tid*16+j] - mx);
    float inv = 1.0f / sum;
    for (int j = 0; j < 16; ++j) s_aw[tid*16+j] = __expf(s_aw[tid*16+j] - mx) * inv;
  }
  __syncthreads();
  int h = tid >> 5, d = tid & 31;
  const int dims[4]   = {128, 64, 32, 16};
  const int starts[4] = {0, 16384, 20480, 21504};
  const __hip_bfloat16* Vb = V + ((size_t)b*S_)*D_ + h*DH + d;
  float acc = 0.f;
  #pragma unroll
  for (int l = 0; l < 4; ++l) {
    int Wl = dims[l], st = starts[l];
    #pragma unroll
    for (int p = 0; p < 4; ++p) {
      float lx = s_loc[h*32 + l*8 + p*2 + 0];
      float ly = s_loc[h*32 + l*8 + p*2 + 1];
      float x = lx * Wl - 0.5f, y = ly * Wl - 0.5f;
      float x0f = floorf(x), y0f = floorf(y);
      float fx = x - x0f, fy = y - y0f;
      int x0 = (int)x0f, y0 = (int)y0f;
      float v = 0.f;
      #pragma unroll
      for (int ty = 0; ty < 2; ++ty) {
        int yi = y0 + ty;
        float wy = ty ? fy : (1.f - fy);
        if (yi < 0 || yi >= Wl) continue;
        #pragma unroll
        for (int txi = 0; txi < 2; ++txi) {
          int xi = x0 + txi;
          float wx = txi ? fx : (1.f - fx);
          if (xi < 0 || xi >= Wl) continue;
          v += wy * wx * __bfloat162float(Vb[(size_t)(st + yi*Wl + xi) * D_]);
        }
      }
      acc += s_aw[h*16 + l*4 + p] * v;
    }
  }
  out[(size_t)row*D_ + tid] = acc;
}

// ================================================================ launch
extern "C" void kernel_launch(void* const* d_in, const int* in_sizes, int n_in,
                              void* d_out, int out_size, void* d_ws, size_t ws_size,
                              hipStream_t stream)
{
  const float* tgt    = (const float*)d_in[0];
  const float* memory = (const float*)d_in[1];
  const float* qpos   = (const float*)d_in[2];
  const float* boxes  = (const float*)d_in[3];
  const float* refp   = (const float*)d_in[4];
  const float* wq = (const float*)d_in[5];   const float* bq = (const float*)d_in[6];
  const float* wk = (const float*)d_in[7];   const float* bk = (const float*)d_in[8];
  const float* wv = (const float*)d_in[9];   const float* bv = (const float*)d_in[10];
  const float* sa_wo = (const float*)d_in[11]; const float* sa_bo = (const float*)d_in[12];
  const float* n1g = (const float*)d_in[13]; const float* n1b = (const float*)d_in[14];
  const float* off_w = (const float*)d_in[15]; const float* off_b = (const float*)d_in[16];
  const float* aw_w  = (const float*)d_in[17]; const float* aw_b  = (const float*)d_in[18];
  const float* val_w = (const float*)d_in[19]; const float* val_b = (const float*)d_in[20];
  const float* co_w  = (const float*)d_in[21]; const float* co_b  = (const float*)d_in[22];
  const float* n2g = (const float*)d_in[23]; const float* n2b = (const float*)d_in[24];
  const float* ff1_w = (const float*)d_in[25]; const float* ff1_b = (const float*)d_in[26];
  const float* ff2_w = (const float*)d_in[27]; const float* ff2_b = (const float*)d_in[28];
  const float* n3g = (const float*)d_in[29]; const float* n3b = (const float*)d_in[30];

  char* ws = (char*)d_ws;
  size_t NE = (size_t)NROWS * D_;
  __hip_bfloat16* Vv = (__hip_bfloat16*)ws;
  float* FFM = (float*)ws;
  size_t p = (size_t)B_ * S_ * D_ * sizeof(__hip_bfloat16);
  float* A  = (float*)(ws + p); p += NE*4;
  float* Qb = (float*)(ws + p); p += NE*4;   // bf16 Q lives here (uses half)
  float* Kb = (float*)(ws + p); p += NE*4;   // bf16 K / later aw-logits (fp32)
  float* Vh = (float*)(ws + p); p += NE*4;   // bf16 Vt (transposed) lives here
  float* S1 = (float*)(ws + p); p += NE*4;
  float* S2 = (float*)(ws + p); p += NE*4;
  float* T1 = (float*)(ws + p); p += NE*4;
  float* out = (float*)d_out;
  (void)ws_size; (void)in_sizes; (void)n_in; (void)out_size;

  dim3 g64(4, (NROWS + 63) / 64);

  // self-attention branch
  rope_kernel<<<NROWS, 128, 0, stream>>>(tgt, qpos, boxes, A);
  gemm_kernel<false,__hip_bfloat16><<<g64, 256, 0, stream>>>(
      A,   wq, bq, (__hip_bfloat16*)Qb, NROWS, 256, 256);
  gemm_kernel<false,__hip_bfloat16><<<g64, 256, 0, stream>>>(
      A,   wk, bk, (__hip_bfloat16*)Kb, NROWS, 256, 256);
  gemm_tv_kernel<<<g64, 256, 0, stream>>>(
      tgt, wv, bv, (__hip_bfloat16*)Vh, NROWS, 256, 256);
  mfma_attn_kernel<<<57 * B_ * H_, 64, 0, stream>>>(
      (const __hip_bfloat16*)Qb, (const __hip_bfloat16*)Kb,
      (const __hip_bfloat16*)Vh, S1);
  gemm_kernel<false,float><<<g64, 256, 0, stream>>>(S1, sa_wo, sa_bo, S2, NROWS, 256, 256);
  add_ln_kernel<<<NROWS, 256, 0, stream>>>(tgt, S2, n1g, n1b, T1);

  // cross-attention branch
  gemm_kernel<false,__hip_bfloat16><<<dim3(4, (B_*S_ + 63)/64), 256, 0, stream>>>(
      memory, val_w, val_b, Vv, B_*S_, 256, 256);
  add_kernel<<<(int)((NE + 255)/256), 256, 0, stream>>>(T1, qpos, A, (int)NE);
  gemm_kernel<false,float><<<g64, 256, 0, stream>>>(A, off_w, off_b, Qb, NROWS, 256, 256);
  gemm_kernel<false,float><<<dim3(2, (NROWS + 63)/64), 256, 0, stream>>>(
      A, aw_w, aw_b, Kb, NROWS, 128, 256);
  sample_kernel<<<NROWS, 256, 0, stream>>>(Vv, Qb, Kb, refp, S1);
  gemm_kernel<false,float><<<g64, 256, 0, stream>>>(S1, co_w, co_b, S2, NROWS, 256, 256);
  add_ln_kernel<<<NROWS, 256, 0, stream>>>(T1, S2, n2g, n2b, T1);

  // ffn
  gemm_kernel<true,float><<<dim3(FF_/64, (NROWS + 63)/64), 256, 0, stream>>>(
      T1, ff1_w, ff1_b, FFM, NROWS, FF_, 256);
  gemm_kernel<false,float><<<g64, 256, 0, stream>>>(FFM, ff2_w, ff2_b, S2, NROWS, 256, FF_);
  add_ln_kernel<<<NROWS, 256, 0, stream>>>(T1, S2, n3g, n3b, out);
}

// Round 3
// 622.833 us; speedup vs baseline: 1.8638x; 1.4382x over previous
//
#include <hip/hip_runtime.h>
#include <hip/hip_bf16.h>
#include <math.h>

#define B_ 8
#define N_ 900
#define D_ 256
#define S_ 21760
#define H_ 8
#define DH 32
#define FF_ 2048
#define NROWS (B_*N_)   // 7200

typedef __attribute__((ext_vector_type(8))) short bf16x8;
typedef __attribute__((ext_vector_type(4))) float f32x4;

static __device__ inline short f2bf_s(float x) {
  __hip_bfloat16 h = __float2bfloat16(x);
  return *reinterpret_cast<short*>(&h);
}

// ---------------------------------------------------------------- RoPE
__global__ __launch_bounds__(128) void rope_kernel(
    const float* __restrict__ tgt, const float* __restrict__ qpos,
    const float* __restrict__ boxes, float* __restrict__ out)
{
  int row = blockIdx.x;
  int tid = threadIdx.x;
  const float* x = tgt  + (size_t)row * D_;
  const float* p = qpos + (size_t)row * D_;
  float a0 = x[2*tid]   + p[2*tid];
  float a1 = x[2*tid+1] + p[2*tid+1];
  float o0 = a0, o1 = a1;
  if (tid < 126) {
    int band = tid / 42;
    int fi   = tid - band * 42;
    float freq = powf(10000.0f, -(float)fi / 42.0f);
    float cx = boxes[(size_t)row*4 + 0];
    float cy = boxes[(size_t)row*4 + 1];
    float v  = (band == 0) ? cx : (band == 1 ? cy : cx * cy);
    if (band == 2) freq *= 0.1f;
    float ang = v * freq;
    float c = cosf(ang), s = sinf(ang);
    o0 = a0 * c - a1 * s;
    o1 = a1 * c + a0 * s;
  }
  out[(size_t)row*D_ + 2*tid]   = o0;
  out[(size_t)row*D_ + 2*tid+1] = o1;
}

// ---------------------------------------------------------------- weight transpose+convert
__global__ __launch_bounds__(256) void wtrans_kernel(
    const float* __restrict__ wq, const float* __restrict__ wk,
    const float* __restrict__ wv, const float* __restrict__ sa_wo,
    const float* __restrict__ offw, const float* __restrict__ valw,
    const float* __restrict__ cow, const float* __restrict__ aww,
    const float* __restrict__ ff1w, const float* __restrict__ ff2w,
    short* __restrict__ Wt)
{
  int bid = blockIdx.x;
  const float* W; short* out; int K, N, tile;
  if (bid < 448) {
    int wi = bid >> 6; tile = bid & 63; K = 256; N = 256;
    const float* tab[7] = {wq, wk, wv, sa_wo, offw, valw, cow};
    W = tab[wi]; out = Wt + wi * 65536;
  } else if (bid < 480) {
    tile = bid - 448; K = 256; N = 128; W = aww; out = Wt + 458752;
  } else if (bid < 992) {
    tile = bid - 480; K = 256; N = 2048; W = ff1w; out = Wt + 491520;
  } else {
    tile = bid - 992; K = 2048; N = 256; W = ff2w; out = Wt + 1015808;
  }
  int ntn = N >> 5;
  int tk = tile / ntn, tn = tile - tk * ntn;
  __shared__ float t[32][33];
  int c = threadIdx.x & 31, rr = threadIdx.x >> 5;
  #pragma unroll
  for (int i = 0; i < 4; ++i)
    t[rr + i*8][c] = W[(size_t)(tk*32 + rr + i*8) * N + tn*32 + c];
  __syncthreads();
  #pragma unroll
  for (int i = 0; i < 4; ++i)
    out[(size_t)(tn*32 + rr + i*8) * K + tk*32 + c] = f2bf_s(t[c][rr + i*8]);
}

// ---------------------------------------------------------------- MFMA GEMM
// C[M,N] = A[M,K] @ W[K,N] + bias, W given as Wt[N][K] bf16.
// BM=64, BN in {256,128}, BK=32, 256 threads (4 waves), 16x16x32 MFMA.
// OUTMODE: 0 = fp32 row-major, 1 = bf16 row-major, 2 = bf16 attn-V transposed.
template<int BN, bool RELU, bool ABF16, int OUTMODE>
__global__ __launch_bounds__(256) void mgemm_kernel(
    const void* __restrict__ Ap, const short* __restrict__ Wt,
    const float* __restrict__ bias, void* __restrict__ Cp,
    int M, int N, int K)
{
  constexpr int WAVES_N = BN / 64;       // 4 or 2
  constexpr int WAVES_M = 4 / WAVES_N;   // 1 or 2
  constexpr int MS = 4 / WAVES_M;        // m-subtiles per wave
  __shared__ short As[64][40];           // bf16, padded row stride 80 B
  int tid = threadIdx.x;
  int w = tid >> 6, lane = tid & 63;
  int g = lane >> 4, r = lane & 15;
  int wn = w % WAVES_N, wm = w / WAVES_N;
  int m0 = blockIdx.x * 64;
  int mw = wm * (MS * 16);
  int n0 = blockIdx.y * BN + wn * 64;
  f32x4 acc[MS][4];
  #pragma unroll
  for (int i = 0; i < MS; ++i)
    #pragma unroll
    for (int j = 0; j < 4; ++j) acc[i][j] = (f32x4){0.f,0.f,0.f,0.f};

  int srow = tid >> 2, sk = (tid & 3) * 8;
  bool svalid = (m0 + srow < M);
  const float* Af = (const float*)Ap;
  const short* Ab = (const short*)Ap;
  union BU { bf16x8 v; short s[8]; unsigned long long u[2]; };

  for (int k0 = 0; k0 < K; k0 += 32) {
    BU pk;
    #pragma unroll
    for (int i = 0; i < 8; ++i) pk.s[i] = 0;
    if (ABF16) {
      if (svalid) pk.v = *(const bf16x8*)&Ab[(size_t)(m0+srow)*K + k0 + sk];
    } else {
      if (svalid) {
        float4 a0 = *(const float4*)&Af[(size_t)(m0+srow)*K + k0 + sk];
        float4 a1 = *(const float4*)&Af[(size_t)(m0+srow)*K + k0 + sk + 4];
        pk.s[0]=f2bf_s(a0.x); pk.s[1]=f2bf_s(a0.y); pk.s[2]=f2bf_s(a0.z); pk.s[3]=f2bf_s(a0.w);
        pk.s[4]=f2bf_s(a1.x); pk.s[5]=f2bf_s(a1.y); pk.s[6]=f2bf_s(a1.z); pk.s[7]=f2bf_s(a1.w);
      }
    }
    __syncthreads();
    *(bf16x8*)&As[srow][sk] = pk.v;
    __syncthreads();

    BU bfr[4];
    #pragma unroll
    for (int ns = 0; ns < 4; ++ns) {
      const short* wp = Wt + (size_t)(n0 + ns*16 + r) * K + k0;
      bfr[ns].u[0] = *(const unsigned long long*)(wp + 4*g);
      bfr[ns].u[1] = *(const unsigned long long*)(wp + 16 + 4*g);
    }
    #pragma unroll
    for (int ms = 0; ms < MS; ++ms) {
      BU af;
      const short* ap = &As[mw + ms*16 + r][0];
      af.u[0] = *(const unsigned long long*)(ap + 4*g);
      af.u[1] = *(const unsigned long long*)(ap + 16 + 4*g);
      #pragma unroll
      for (int ns = 0; ns < 4; ++ns)
        acc[ms][ns] = __builtin_amdgcn_mfma_f32_16x16x32_bf16(af.v, bfr[ns].v, acc[ms][ns], 0, 0, 0);
    }
  }

  #pragma unroll
  for (int ms = 0; ms < MS; ++ms) {
    #pragma unroll
    for (int ns = 0; ns < 4; ++ns) {
      int n = n0 + ns*16 + r;
      float bs = bias[n];
      #pragma unroll
      for (int j = 0; j < 4; ++j) {
        int m = m0 + mw + ms*16 + g*4 + j;
        if (m >= M) continue;
        float v = acc[ms][ns][j] + bs;
        if (RELU) v = fmaxf(v, 0.f);
        if (OUTMODE == 0) {
          ((float*)Cp)[(size_t)m*N + n] = v;
        } else if (OUTMODE == 1) {
          ((short*)Cp)[(size_t)m*N + n] = f2bf_s(v);
        } else {
          int bb = m / N_, nn = m - bb * N_;
          int hh = n >> 5, dd = n & 31;
          ((short*)Cp)[((size_t)((bb*H_ + hh)*DH + dd))*N_ + nn] = f2bf_s(v);
        }
      }
    }
  }
}

// ---------------------------------------------------------------- MFMA flash attention
__global__ __launch_bounds__(64) void mfma_attn_kernel(
    const __hip_bfloat16* __restrict__ Q,
    const __hip_bfloat16* __restrict__ K,
    const __hip_bfloat16* __restrict__ Vt,
    float* __restrict__ O)
{
  const int NQT = 57;
  int wid = blockIdx.x;
  int qt = wid % NQT, bh = wid / NQT;
  int b = bh >> 3, h = bh & 7;
  int lane = threadIdx.x;
  int g = lane >> 4, r = lane & 15;
  int q0 = qt * 16;
  const float scale = 0.17677669529663687f;

  union U { bf16x8 v; short s[8]; unsigned long long u64[2]; };

  U qf;
  {
    int qrow = min(q0 + r, N_ - 1);
    const __hip_bfloat16* qp = Q + ((size_t)(b*N_ + qrow))*D_ + h*DH;
    qf.u64[0] = *(const unsigned long long*)(qp + 4*g);
    qf.u64[1] = *(const unsigned long long*)(qp + 16 + 4*g);
  }

  f32x4 oacc0 = {0.f,0.f,0.f,0.f};
  f32x4 oacc1 = {0.f,0.f,0.f,0.f};
  float m = -1e30f, l = 0.0f;
  const f32x4 zero = {0.f,0.f,0.f,0.f};

  const __hip_bfloat16* vbase0 = Vt + (size_t)(bh*DH + r) * N_;
  const __hip_bfloat16* vbase1 = Vt + (size_t)(bh*DH + 16 + r) * N_;

  for (int kt = 0; kt < N_; kt += 32) {
    U kf0, kf1;
    {
      int kr0 = min(kt + r, N_ - 1);
      int kr1 = min(kt + 16 + r, N_ - 1);
      const __hip_bfloat16* kp0 = K + ((size_t)(b*N_ + kr0))*D_ + h*DH;
      const __hip_bfloat16* kp1 = K + ((size_t)(b*N_ + kr1))*D_ + h*DH;
      kf0.u64[0] = *(const unsigned long long*)(kp0 + 4*g);
      kf0.u64[1] = *(const unsigned long long*)(kp0 + 16 + 4*g);
      kf1.u64[0] = *(const unsigned long long*)(kp1 + 4*g);
      kf1.u64[1] = *(const unsigned long long*)(kp1 + 16 + 4*g);
    }
    f32x4 s0 = __builtin_amdgcn_mfma_f32_16x16x32_bf16(kf0.v, qf.v, zero, 0, 0, 0);
    f32x4 s1 = __builtin_amdgcn_mfma_f32_16x16x32_bf16(kf1.v, qf.v, zero, 0, 0, 0);

    float sc[8];
    #pragma unroll
    for (int j = 0; j < 4; ++j) {
      sc[j]   = (kt + 4*g + j      < N_) ? s0[j] * scale : -1e30f;
      sc[4+j] = (kt + 16 + 4*g + j < N_) ? s1[j] * scale : -1e30f;
    }
    float mx = sc[0];
    #pragma unroll
    for (int j = 1; j < 8; ++j) mx = fmaxf(mx, sc[j]);
    mx = fmaxf(mx, __shfl_xor(mx, 16));
    mx = fmaxf(mx, __shfl_xor(mx, 32));

    float mnew = fmaxf(m, mx);
    float corr = __expf(m - mnew);
    float p[8], ps = 0.f;
    #pragma unroll
    for (int j = 0; j < 8; ++j) { p[j] = __expf(sc[j] - mnew); ps += p[j]; }
    ps += __shfl_xor(ps, 16);
    ps += __shfl_xor(ps, 32);
    l = l * corr + ps;
    m = mnew;
    #pragma unroll
    for (int j = 0; j < 4; ++j) { oacc0[j] *= corr; oacc1[j] *= corr; }

    U pf;
    #pragma unroll
    for (int j = 0; j < 8; ++j) pf.s[j] = f2bf_s(p[j]);

    U vf0, vf1;
    vf0.u64[0] = *(const unsigned long long*)(vbase0 + kt + 4*g);
    vf0.u64[1] = *(const unsigned long long*)(vbase0 + kt + 16 + 4*g);
    vf1.u64[0] = *(const unsigned long long*)(vbase1 + kt + 4*g);
    vf1.u64[1] = *(const unsigned long long*)(vbase1 + kt + 16 + 4*g);

    oacc0 = __builtin_amdgcn_mfma_f32_16x16x32_bf16(vf0.v, pf.v, oacc0, 0, 0, 0);
    oacc1 = __builtin_amdgcn_mfma_f32_16x16x32_bf16(vf1.v, pf.v, oacc1, 0, 0, 0);
  }

  if (q0 + r < N_) {
    float inv = 1.0f / l;
    float* op = O + ((size_t)(b*N_ + q0 + r))*D_ + h*DH;
    #pragma unroll
    for (int j = 0; j < 4; ++j) {
      op[4*g + j]      = oacc0[j] * inv;
      op[16 + 4*g + j] = oacc1[j] * inv;
    }
  }
}

// ---------------------------------------------------------------- add + LayerNorm
__global__ __launch_bounds__(256) void add_ln_kernel(
    const float* __restrict__ X, const float* __restrict__ Y,
    const float* __restrict__ g, const float* __restrict__ beta,
    float* __restrict__ out)
{
  int row = blockIdx.x, tid = threadIdx.x;
  float v = X[(size_t)row*D_ + tid] + Y[(size_t)row*D_ + tid];
  float s = v, s2 = v*v;
  #pragma unroll
  for (int off = 32; off; off >>= 1) {
    s  += __shfl_down(s,  off, 64);
    s2 += __shfl_down(s2, off, 64);
  }
  __shared__ float red[8];
  int wid = tid >> 6, lane = tid & 63;
  if (lane == 0) { red[wid] = s; red[wid+4] = s2; }
  __syncthreads();
  if (tid == 0) {
    float ts  = red[0]+red[1]+red[2]+red[3];
    float ts2 = red[4]+red[5]+red[6]+red[7];
    float mu  = ts * (1.0f/D_);
    float var = ts2 * (1.0f/D_) - mu*mu;
    red[0] = mu;
    red[1] = rsqrtf(fmaxf(var, 0.0f) + 1e-5f);
  }
  __syncthreads();
  float mu = red[0], rr = red[1];
  out[(size_t)row*D_ + tid] = (v - mu)*rr*g[tid] + beta[tid];
}

// ---------------------------------------------------------------- elementwise add
__global__ __launch_bounds__(256) void add_kernel(
    const float* __restrict__ a, const float* __restrict__ b,
    float* __restrict__ c, int n)
{
  int i = blockIdx.x * 256 + threadIdx.x;
  if (i < n) c[i] = a[i] + b[i];
}

// ---------------------------------------------------------------- deformable sampling
__global__ __launch_bounds__(256) void sample_kernel(
    const __hip_bfloat16* __restrict__ V, const float* __restrict__ offp,
    const float* __restrict__ awl, const float* __restrict__ refp,
    float* __restrict__ out)
{
  int row = blockIdx.x;
  int b = row / N_;
  int tid = threadIdx.x;
  __shared__ float s_aw[128];
  __shared__ float s_loc[256];
  if (tid < 128) s_aw[tid] = awl[(size_t)row*128 + tid];
  {
    int rem = tid & 31;
    int l = rem >> 3, ax = rem & 1;
    const float norms[4] = {128.f, 64.f, 32.f, 16.f};
    float off = offp[(size_t)row*256 + tid];
    float rp  = refp[((size_t)row*4 + l)*2 + ax];
    s_loc[tid] = rp + off / norms[l];
  }
  __syncthreads();
  if (tid < 8) {
    float mx = -1e30f;
    for (int j = 0; j < 16; ++j) mx = fmaxf(mx, s_aw[tid*16+j]);
    float sum = 0.f;
    for (int j = 0; j < 16; ++j) sum += __expf(s_aw[tid*16+j] - mx);
    float inv = 1.0f / sum;
    for (int j = 0; j < 16; ++j) s_aw[tid*16+j] = __expf(s_aw[tid*16+j] - mx) * inv;
  }
  __syncthreads();
  int h = tid >> 5, d = tid & 31;
  const int dims[4]   = {128, 64, 32, 16};
  const int starts[4] = {0, 16384, 20480, 21504};
  const __hip_bfloat16* Vb = V + ((size_t)b*S_)*D_ + h*DH + d;
  float acc = 0.f;
  #pragma unroll
  for (int l = 0; l < 4; ++l) {
    int Wl = dims[l], st = starts[l];
    #pragma unroll
    for (int p = 0; p < 4; ++p) {
      float lx = s_loc[h*32 + l*8 + p*2 + 0];
      float ly = s_loc[h*32 + l*8 + p*2 + 1];
      float x = lx * Wl - 0.5f, y = ly * Wl - 0.5f;
      float x0f = floorf(x), y0f = floorf(y);
      float fx = x - x0f, fy = y - y0f;
      int x0 = (int)x0f, y0 = (int)y0f;
      float v = 0.f;
      #pragma unroll
      for (int ty = 0; ty < 2; ++ty) {
        int yi = y0 + ty;
        float wy = ty ? fy : (1.f - fy);
        if (yi < 0 || yi >= Wl) continue;
        #pragma unroll
        for (int txi = 0; txi < 2; ++txi) {
          int xi = x0 + txi;
          float wx = txi ? fx : (1.f - fx);
          if (xi < 0 || xi >= Wl) continue;
          v += wy * wx * __bfloat162float(Vb[(size_t)(st + yi*Wl + xi) * D_]);
        }
      }
      acc += s_aw[h*16 + l*4 + p] * v;
    }
  }
  out[(size_t)row*D_ + tid] = acc;
}

// ================================================================ launch
extern "C" void kernel_launch(void* const* d_in, const int* in_sizes, int n_in,
                              void* d_out, int out_size, void* d_ws, size_t ws_size,
                              hipStream_t stream)
{
  const float* tgt    = (const float*)d_in[0];
  const float* memory = (const float*)d_in[1];
  const float* qpos   = (const float*)d_in[2];
  const float* boxes  = (const float*)d_in[3];
  const float* refp   = (const float*)d_in[4];
  const float* wq = (const float*)d_in[5];   const float* bq = (const float*)d_in[6];
  const float* wk = (const float*)d_in[7];   const float* bk = (const float*)d_in[8];
  const float* wv = (const float*)d_in[9];   const float* bv = (const float*)d_in[10];
  const float* sa_wo = (const float*)d_in[11]; const float* sa_bo = (const float*)d_in[12];
  const float* n1g = (const float*)d_in[13]; const float* n1b = (const float*)d_in[14];
  const float* off_w = (const float*)d_in[15]; const float* off_b = (const float*)d_in[16];
  const float* aw_w  = (const float*)d_in[17]; const float* aw_b  = (const float*)d_in[18];
  const float* val_w = (const float*)d_in[19]; const float* val_b = (const float*)d_in[20];
  const float* co_w  = (const float*)d_in[21]; const float* co_b  = (const float*)d_in[22];
  const float* n2g = (const float*)d_in[23]; const float* n2b = (const float*)d_in[24];
  const float* ff1_w = (const float*)d_in[25]; const float* ff1_b = (const float*)d_in[26];
  const float* ff2_w = (const float*)d_in[27]; const float* ff2_b = (const float*)d_in[28];
  const float* n3g = (const float*)d_in[29]; const float* n3b = (const float*)d_in[30];

  char* ws = (char*)d_ws;
  size_t NE = (size_t)NROWS * D_;
  __hip_bfloat16* Vv = (__hip_bfloat16*)ws;
  __hip_bfloat16* FFM = (__hip_bfloat16*)ws;
  size_t p = (size_t)B_ * S_ * D_ * sizeof(__hip_bfloat16);
  float* A  = (float*)(ws + p); p += NE*4;
  float* Qb = (float*)(ws + p); p += NE*4;
  float* Kb = (float*)(ws + p); p += NE*4;
  float* Vh = (float*)(ws + p); p += NE*4;
  float* S1 = (float*)(ws + p); p += NE*4;
  float* S2 = (float*)(ws + p); p += NE*4;
  float* T1 = (float*)(ws + p); p += NE*4;
  short* Wt = (short*)((char*)Kb + NE*2);   // free tail half of Kb (3.08 MB <= 3.68 MB)
  float* out = (float*)d_out;
  (void)ws_size; (void)in_sizes; (void)n_in; (void)out_size;

  const short* wq_t  = Wt;
  const short* wk_t  = Wt + 65536;
  const short* wv_t  = Wt + 131072;
  const short* sa_t  = Wt + 196608;
  const short* off_t = Wt + 262144;
  const short* val_t = Wt + 327680;
  const short* co_t  = Wt + 393216;
  const short* aw_t  = Wt + 458752;
  const short* ff1_t = Wt + 491520;
  const short* ff2_t = Wt + 1015808;

  wtrans_kernel<<<1504, 256, 0, stream>>>(wq, wk, wv, sa_wo, off_w, val_w,
                                          co_w, aw_w, ff1_w, ff2_w, Wt);

  dim3 gS(113, 1);
  rope_kernel<<<NROWS, 128, 0, stream>>>(tgt, qpos, boxes, A);
  mgemm_kernel<256,false,false,1><<<gS, 256, 0, stream>>>(A,   wq_t, bq, Qb, NROWS, 256, 256);
  mgemm_kernel<256,false,false,1><<<gS, 256, 0, stream>>>(A,   wk_t, bk, Kb, NROWS, 256, 256);
  mgemm_kernel<256,false,false,2><<<gS, 256, 0, stream>>>(tgt, wv_t, bv, Vh, NROWS, 256, 256);
  mfma_attn_kernel<<<57 * B_ * H_, 64, 0, stream>>>(
      (const __hip_bfloat16*)Qb, (const __hip_bfloat16*)Kb,
      (const __hip_bfloat16*)Vh, S1);
  mgemm_kernel<256,false,false,0><<<gS, 256, 0, stream>>>(S1, sa_t, sa_bo, S2, NROWS, 256, 256);
  add_ln_kernel<<<NROWS, 256, 0, stream>>>(tgt, S2, n1g, n1b, T1);

  mgemm_kernel<256,false,false,1><<<dim3(2720,1), 256, 0, stream>>>(
      memory, val_t, val_b, Vv, B_*S_, 256, 256);
  add_kernel<<<(int)((NE + 255)/256), 256, 0, stream>>>(T1, qpos, A, (int)NE);
  mgemm_kernel<256,false,false,0><<<gS, 256, 0, stream>>>(A, off_t, off_b, Qb, NROWS, 256, 256);
  mgemm_kernel<128,false,false,0><<<gS, 256, 0, stream>>>(A, aw_t, aw_b, Kb, NROWS, 128, 256);
  sample_kernel<<<NROWS, 256, 0, stream>>>(Vv, Qb, Kb, refp, S1);
  mgemm_kernel<256,false,false,0><<<gS, 256, 0, stream>>>(S1, co_t, co_b, S2, NROWS, 256, 256);
  add_ln_kernel<<<NROWS, 256, 0, stream>>>(T1, S2, n2g, n2b, T1);

  mgemm_kernel<256,true,false,1><<<dim3(113,8), 256, 0, stream>>>(
      T1, ff1_t, ff1_b, FFM, NROWS, FF_, 256);
  mgemm_kernel<256,false,true,0><<<gS, 256, 0, stream>>>(FFM, ff2_t, ff2_b, S2, NROWS, 256, FF_);
  add_ln_kernel<<<NROWS, 256, 0, stream>>>(T1, S2, n3g, n3b, out);
}

// Round 4
// 524.654 us; speedup vs baseline: 2.2126x; 1.1871x over previous
//
#include <hip/hip_runtime.h>
#include <hip/hip_bf16.h>
#include <math.h>

#define B_ 8
#define N_ 900
#define D_ 256
#define S_ 21760
#define H_ 8
#define DH 32
#define FF_ 2048
#define NROWS (B_*N_)   // 7200

typedef __attribute__((ext_vector_type(8))) short bf16x8;
typedef __attribute__((ext_vector_type(4))) float f32x4;

union BU { bf16x8 v; short s[8]; unsigned long long u[2]; };

static __device__ inline short f2bf_s(float x) {
  __hip_bfloat16 h = __float2bfloat16(x);
  return *reinterpret_cast<short*>(&h);
}

// ---------------------------------------------------------------- RoPE
__global__ __launch_bounds__(128) void rope_kernel(
    const float* __restrict__ tgt, const float* __restrict__ qpos,
    const float* __restrict__ boxes, float* __restrict__ out)
{
  int row = blockIdx.x;
  int tid = threadIdx.x;
  const float* x = tgt  + (size_t)row * D_;
  const float* p = qpos + (size_t)row * D_;
  float a0 = x[2*tid]   + p[2*tid];
  float a1 = x[2*tid+1] + p[2*tid+1];
  float o0 = a0, o1 = a1;
  if (tid < 126) {
    int band = tid / 42;
    int fi   = tid - band * 42;
    float freq = powf(10000.0f, -(float)fi / 42.0f);
    float cx = boxes[(size_t)row*4 + 0];
    float cy = boxes[(size_t)row*4 + 1];
    float v  = (band == 0) ? cx : (band == 1 ? cy : cx * cy);
    if (band == 2) freq *= 0.1f;
    float ang = v * freq;
    float c = cosf(ang), s = sinf(ang);
    o0 = a0 * c - a1 * s;
    o1 = a1 * c + a0 * s;
  }
  out[(size_t)row*D_ + 2*tid]   = o0;
  out[(size_t)row*D_ + 2*tid+1] = o1;
}

// ---------------------------------------------------------------- weight transpose+convert
// Layout (elems): qk 0 (wq@0, wk@65536 adjacent), wv 131072, sa 196608,
// off 262144, aw 327680 (adjacent to off), val 360448, co 425984,
// ff1 491520, ff2 1015808.  Total 1540096 shorts.
__global__ __launch_bounds__(256) void wtrans_kernel(
    const float* __restrict__ wq, const float* __restrict__ wk,
    const float* __restrict__ wv, const float* __restrict__ sa_wo,
    const float* __restrict__ offw, const float* __restrict__ valw,
    const float* __restrict__ cow, const float* __restrict__ aww,
    const float* __restrict__ ff1w, const float* __restrict__ ff2w,
    short* __restrict__ Wt)
{
  int bid = blockIdx.x;
  const float* W; short* out; int K, N, tile;
  if (bid < 448) {
    int wi = bid >> 6; tile = bid & 63; K = 256; N = 256;
    const float* tab[7] = {wq, wk, wv, sa_wo, offw, valw, cow};
    const int   off[7]  = {0, 65536, 131072, 196608, 262144, 360448, 425984};
    W = tab[wi]; out = Wt + off[wi];
  } else if (bid < 480) {
    tile = bid - 448; K = 256; N = 128; W = aww; out = Wt + 327680;
  } else if (bid < 992) {
    tile = bid - 480; K = 256; N = 2048; W = ff1w; out = Wt + 491520;
  } else {
    tile = bid - 992; K = 2048; N = 256; W = ff2w; out = Wt + 1015808;
  }
  int ntn = N >> 5;
  int tk = tile / ntn, tn = tile - tk * ntn;
  __shared__ float t[32][33];
  int c = threadIdx.x & 31, rr = threadIdx.x >> 5;
  #pragma unroll
  for (int i = 0; i < 4; ++i)
    t[rr + i*8][c] = W[(size_t)(tk*32 + rr + i*8) * N + tn*32 + c];
  __syncthreads();
  #pragma unroll
  for (int i = 0; i < 4; ++i)
    out[(size_t)(tn*32 + rr + i*8) * K + tk*32 + c] = f2bf_s(t[c][rr + i*8]);
}

// ---------------------------------------------------------------- MFMA GEMM
// C[M,N] = A[M,K] @ W + bias, W as Wt[N][K] bf16 (L2-resident).
// Whole 256-wide K-strip staged in LDS (XOR-swizzled), fully-unrolled MFMA
// loop with zero barriers inside -> deep pipelining of L2 B-loads.
// 4 waves; wave w owns cols [nw, nw+64), all BM rows. M % BM == 0 assumed.
// OUTMODE: 0 fp32 [M][N]; 1 bf16 [M][N]; 2 bf16 attn-V transpose;
//          3 dual bf16 (n<256 -> Cp[.][256], else Cp2[.][256]);
//          4 dual fp32 (n<256 -> Cp[.][256], else Cp2[.][128]).
template<int BM, int KK, bool ABF16, bool A2ADD, bool RELU, int OUTMODE>
__global__ __launch_bounds__(256) void mgemm_kernel(
    const void* __restrict__ Ap, const float* __restrict__ A2p,
    const short* __restrict__ Wt,
    const float* __restrict__ bias, const float* __restrict__ bias2,
    void* __restrict__ Cp, void* __restrict__ Cp2, int M, int N)
{
  constexpr int MS = BM / 16;
  __shared__ short As[BM * 256];
  int tid = threadIdx.x;
  int w = tid >> 6, lane = tid & 63;
  int g = lane >> 4, r = lane & 15;
  int m0 = blockIdx.x * BM;
  int nw = blockIdx.y * 256 + w * 64;
  bool active = nw < N;

  f32x4 acc[MS][4];
  #pragma unroll
  for (int i = 0; i < MS; ++i)
    #pragma unroll
    for (int j = 0; j < 4; ++j) acc[i][j] = (f32x4){0.f,0.f,0.f,0.f};

  for (int kb = 0; kb < KK; kb += 256) {
    if (KK > 256 && kb) __syncthreads();
    // ---- stage A strip [BM][256] -> bf16 LDS, swizzled
    #pragma unroll
    for (int i = 0; i < BM/8; ++i) {
      int u = i*256 + tid;
      int row = u >> 5, c8 = u & 31;
      BU pk;
      if (ABF16) {
        pk.v = *(const bf16x8*)((const short*)Ap + (size_t)(m0+row)*KK + kb + c8*8);
      } else {
        const float* ap = (const float*)Ap + (size_t)(m0+row)*KK + kb + c8*8;
        float4 a0 = *(const float4*)ap;
        float4 a1 = *(const float4*)(ap + 4);
        if (A2ADD) {
          const float* a2 = A2p + (size_t)(m0+row)*KK + kb + c8*8;
          float4 b0 = *(const float4*)a2;
          float4 b1 = *(const float4*)(a2 + 4);
          a0.x += b0.x; a0.y += b0.y; a0.z += b0.z; a0.w += b0.w;
          a1.x += b1.x; a1.y += b1.y; a1.z += b1.z; a1.w += b1.w;
        }
        pk.s[0]=f2bf_s(a0.x); pk.s[1]=f2bf_s(a0.y); pk.s[2]=f2bf_s(a0.z); pk.s[3]=f2bf_s(a0.w);
        pk.s[4]=f2bf_s(a1.x); pk.s[5]=f2bf_s(a1.y); pk.s[6]=f2bf_s(a1.z); pk.s[7]=f2bf_s(a1.w);
      }
      int col = (c8*8) ^ ((row & 7) << 3);   // shorts; = bytes>>1 swizzle
      *(bf16x8*)&As[row*256 + col] = pk.v;
    }
    __syncthreads();
    if (active) {
      #pragma unroll
      for (int kk = 0; kk < 8; ++kk) {
        BU bfr[4];
        #pragma unroll
        for (int ns = 0; ns < 4; ++ns) {
          const short* wp = Wt + (size_t)(nw + ns*16 + r)*KK + kb + kk*32;
          bfr[ns].u[0] = *(const unsigned long long*)(wp + 4*g);
          bfr[ns].u[1] = *(const unsigned long long*)(wp + 16 + 4*g);
        }
        #pragma unroll
        for (int ms = 0; ms < MS; ++ms) {
          int row = ms*16 + r;
          int c0 = (kk*32 + g*4)      ^ ((r & 7) << 3);
          int c1 = (kk*32 + 16 + g*4) ^ ((r & 7) << 3);
          BU af;
          af.u[0] = *(const unsigned long long*)&As[row*256 + c0];
          af.u[1] = *(const unsigned long long*)&As[row*256 + c1];
          #pragma unroll
          for (int ns = 0; ns < 4; ++ns)
            acc[ms][ns] = __builtin_amdgcn_mfma_f32_16x16x32_bf16(
                af.v, bfr[ns].v, acc[ms][ns], 0, 0, 0);
        }
      }
    }
  }
  if (!active) return;

  #pragma unroll
  for (int ms = 0; ms < MS; ++ms) {
    #pragma unroll
    for (int ns = 0; ns < 4; ++ns) {
      int n = nw + ns*16 + r;
      float bs;
      if (OUTMODE == 3 || OUTMODE == 4) bs = (n < 256) ? bias[n] : bias2[n - 256];
      else bs = bias[n];
      #pragma unroll
      for (int j = 0; j < 4; ++j) {
        int m = m0 + ms*16 + g*4 + j;
        float v = acc[ms][ns][j] + bs;
        if (RELU) v = fmaxf(v, 0.f);
        if (OUTMODE == 0) {
          ((float*)Cp)[(size_t)m*N + n] = v;
        } else if (OUTMODE == 1) {
          ((short*)Cp)[(size_t)m*N + n] = f2bf_s(v);
        } else if (OUTMODE == 2) {
          int bb = m / N_, nn = m - bb * N_;
          int hh = n >> 5, dd = n & 31;
          ((short*)Cp)[((size_t)((bb*H_ + hh)*DH + dd))*N_ + nn] = f2bf_s(v);
        } else if (OUTMODE == 3) {
          if (n < 256) ((short*)Cp )[(size_t)m*256 + n]       = f2bf_s(v);
          else         ((short*)Cp2)[(size_t)m*256 + (n-256)] = f2bf_s(v);
        } else {
          if (n < 256) ((float*)Cp )[(size_t)m*256 + n]       = v;
          else         ((float*)Cp2)[(size_t)m*128 + (n-256)] = v;
        }
      }
    }
  }
}

// ---------------------------------------------------------------- MFMA flash attention
__global__ __launch_bounds__(64) void mfma_attn_kernel(
    const __hip_bfloat16* __restrict__ Q,
    const __hip_bfloat16* __restrict__ K,
    const __hip_bfloat16* __restrict__ Vt,
    float* __restrict__ O)
{
  const int NQT = 57;
  int wid = blockIdx.x;
  int qt = wid % NQT, bh = wid / NQT;
  int b = bh >> 3, h = bh & 7;
  int lane = threadIdx.x;
  int g = lane >> 4, r = lane & 15;
  int q0 = qt * 16;
  const float scale = 0.17677669529663687f;

  union U { bf16x8 v; short s[8]; unsigned long long u64[2]; };

  U qf;
  {
    int qrow = min(q0 + r, N_ - 1);
    const __hip_bfloat16* qp = Q + ((size_t)(b*N_ + qrow))*D_ + h*DH;
    qf.u64[0] = *(const unsigned long long*)(qp + 4*g);
    qf.u64[1] = *(const unsigned long long*)(qp + 16 + 4*g);
  }

  f32x4 oacc0 = {0.f,0.f,0.f,0.f};
  f32x4 oacc1 = {0.f,0.f,0.f,0.f};
  float m = -1e30f, l = 0.0f;
  const f32x4 zero = {0.f,0.f,0.f,0.f};

  const __hip_bfloat16* vbase0 = Vt + (size_t)(bh*DH + r) * N_;
  const __hip_bfloat16* vbase1 = Vt + (size_t)(bh*DH + 16 + r) * N_;

  for (int kt = 0; kt < N_; kt += 32) {
    U kf0, kf1;
    {
      int kr0 = min(kt + r, N_ - 1);
      int kr1 = min(kt + 16 + r, N_ - 1);
      const __hip_bfloat16* kp0 = K + ((size_t)(b*N_ + kr0))*D_ + h*DH;
      const __hip_bfloat16* kp1 = K + ((size_t)(b*N_ + kr1))*D_ + h*DH;
      kf0.u64[0] = *(const unsigned long long*)(kp0 + 4*g);
      kf0.u64[1] = *(const unsigned long long*)(kp0 + 16 + 4*g);
      kf1.u64[0] = *(const unsigned long long*)(kp1 + 4*g);
      kf1.u64[1] = *(const unsigned long long*)(kp1 + 16 + 4*g);
    }
    f32x4 s0 = __builtin_amdgcn_mfma_f32_16x16x32_bf16(kf0.v, qf.v, zero, 0, 0, 0);
    f32x4 s1 = __builtin_amdgcn_mfma_f32_16x16x32_bf16(kf1.v, qf.v, zero, 0, 0, 0);

    float sc[8];
    #pragma unroll
    for (int j = 0; j < 4; ++j) {
      sc[j]   = (kt + 4*g + j      < N_) ? s0[j] * scale : -1e30f;
      sc[4+j] = (kt + 16 + 4*g + j < N_) ? s1[j] * scale : -1e30f;
    }
    float mx = sc[0];
    #pragma unroll
    for (int j = 1; j < 8; ++j) mx = fmaxf(mx, sc[j]);
    mx = fmaxf(mx, __shfl_xor(mx, 16));
    mx = fmaxf(mx, __shfl_xor(mx, 32));

    float mnew = fmaxf(m, mx);
    float corr = __expf(m - mnew);
    float p[8], ps = 0.f;
    #pragma unroll
    for (int j = 0; j < 8; ++j) { p[j] = __expf(sc[j] - mnew); ps += p[j]; }
    ps += __shfl_xor(ps, 16);
    ps += __shfl_xor(ps, 32);
    l = l * corr + ps;
    m = mnew;
    #pragma unroll
    for (int j = 0; j < 4; ++j) { oacc0[j] *= corr; oacc1[j] *= corr; }

    U pf;
    #pragma unroll
    for (int j = 0; j < 8; ++j) pf.s[j] = f2bf_s(p[j]);

    U vf0, vf1;
    vf0.u64[0] = *(const unsigned long long*)(vbase0 + kt + 4*g);
    vf0.u64[1] = *(const unsigned long long*)(vbase0 + kt + 16 + 4*g);
    vf1.u64[0] = *(const unsigned long long*)(vbase1 + kt + 4*g);
    vf1.u64[1] = *(const unsigned long long*)(vbase1 + kt + 16 + 4*g);

    oacc0 = __builtin_amdgcn_mfma_f32_16x16x32_bf16(vf0.v, pf.v, oacc0, 0, 0, 0);
    oacc1 = __builtin_amdgcn_mfma_f32_16x16x32_bf16(vf1.v, pf.v, oacc1, 0, 0, 0);
  }

  if (q0 + r < N_) {
    float inv = 1.0f / l;
    float* op = O + ((size_t)(b*N_ + q0 + r))*D_ + h*DH;
    #pragma unroll
    for (int j = 0; j < 4; ++j) {
      op[4*g + j]      = oacc0[j] * inv;
      op[16 + 4*g + j] = oacc1[j] * inv;
    }
  }
}

// ---------------------------------------------------------------- add + LayerNorm
__global__ __launch_bounds__(256) void add_ln_kernel(
    const float* __restrict__ X, const float* __restrict__ Y,
    const float* __restrict__ g, const float* __restrict__ beta,
    float* __restrict__ out)
{
  int row = blockIdx.x, tid = threadIdx.x;
  float v = X[(size_t)row*D_ + tid] + Y[(size_t)row*D_ + tid];
  float s = v, s2 = v*v;
  #pragma unroll
  for (int off = 32; off; off >>= 1) {
    s  += __shfl_down(s,  off, 64);
    s2 += __shfl_down(s2, off, 64);
  }
  __shared__ float red[8];
  int wid = tid >> 6, lane = tid & 63;
  if (lane == 0) { red[wid] = s; red[wid+4] = s2; }
  __syncthreads();
  if (tid == 0) {
    float ts  = red[0]+red[1]+red[2]+red[3];
    float ts2 = red[4]+red[5]+red[6]+red[7];
    float mu  = ts * (1.0f/D_);
    float var = ts2 * (1.0f/D_) - mu*mu;
    red[0] = mu;
    red[1] = rsqrtf(fmaxf(var, 0.0f) + 1e-5f);
  }
  __syncthreads();
  float mu = red[0], rr = red[1];
  out[(size_t)row*D_ + tid] = (v - mu)*rr*g[tid] + beta[tid];
}

// ---------------------------------------------------------------- deformable sampling
__global__ __launch_bounds__(256) void sample_kernel(
    const __hip_bfloat16* __restrict__ V, const float* __restrict__ offp,
    const float* __restrict__ awl, const float* __restrict__ refp,
    float* __restrict__ out)
{
  int row = blockIdx.x;
  int b = row / N_;
  int tid = threadIdx.x;
  __shared__ float s_aw[128];
  __shared__ float s_loc[256];
  if (tid < 128) s_aw[tid] = awl[(size_t)row*128 + tid];
  {
    int rem = tid & 31;
    int l = rem >> 3, ax = rem & 1;
    const float norms[4] = {128.f, 64.f, 32.f, 16.f};
    float off = offp[(size_t)row*256 + tid];
    float rp  = refp[((size_t)row*4 + l)*2 + ax];
    s_loc[tid] = rp + off / norms[l];
  }
  __syncthreads();
  if (tid < 8) {
    float mx = -1e30f;
    for (int j = 0; j < 16; ++j) mx = fmaxf(mx, s_aw[tid*16+j]);
    float sum = 0.f;
    for (int j = 0; j < 16; ++j) sum += __expf(s_aw[tid*16+j] - mx);
    float inv = 1.0f / sum;
    for (int j = 0; j < 16; ++j) s_aw[tid*16+j] = __expf(s_aw[tid*16+j] - mx) * inv;
  }
  __syncthreads();
  int h = tid >> 5, d = tid & 31;
  const int dims[4]   = {128, 64, 32, 16};
  const int starts[4] = {0, 16384, 20480, 21504};
  const __hip_bfloat16* Vb = V + ((size_t)b*S_)*D_ + h*DH + d;
  float acc = 0.f;
  #pragma unroll
  for (int l = 0; l < 4; ++l) {
    int Wl = dims[l], st = starts[l];
    #pragma unroll
    for (int p = 0; p < 4; ++p) {
      float lx = s_loc[h*32 + l*8 + p*2 + 0];
      float ly = s_loc[h*32 + l*8 + p*2 + 1];
      float x = lx * Wl - 0.5f, y = ly * Wl - 0.5f;
      float x0f = floorf(x), y0f = floorf(y);
      float fx = x - x0f, fy = y - y0f;
      int x0 = (int)x0f, y0 = (int)y0f;
      float v = 0.f;
      #pragma unroll
      for (int ty = 0; ty < 2; ++ty) {
        int yi = y0 + ty;
        float wy = ty ? fy : (1.f - fy);
        if (yi < 0 || yi >= Wl) continue;
        #pragma unroll
        for (int txi = 0; txi < 2; ++txi) {
          int xi = x0 + txi;
          float wx = txi ? fx : (1.f - fx);
          if (xi < 0 || xi >= Wl) continue;
          v += wy * wx * __bfloat162float(Vb[(size_t)(st + yi*Wl + xi) * D_]);
        }
      }
      acc += s_aw[h*16 + l*4 + p] * v;
    }
  }
  out[(size_t)row*D_ + tid] = acc;
}

// ================================================================ launch
extern "C" void kernel_launch(void* const* d_in, const int* in_sizes, int n_in,
                              void* d_out, int out_size, void* d_ws, size_t ws_size,
                              hipStream_t stream)
{
  const float* tgt    = (const float*)d_in[0];
  const float* memory = (const float*)d_in[1];
  const float* qpos   = (const float*)d_in[2];
  const float* boxes  = (const float*)d_in[3];
  const float* refp   = (const float*)d_in[4];
  const float* wq = (const float*)d_in[5];   const float* bq = (const float*)d_in[6];
  const float* wk = (const float*)d_in[7];   const float* bk = (const float*)d_in[8];
  const float* wv = (const float*)d_in[9];   const float* bv = (const float*)d_in[10];
  const float* sa_wo = (const float*)d_in[11]; const float* sa_bo = (const float*)d_in[12];
  const float* n1g = (const float*)d_in[13]; const float* n1b = (const float*)d_in[14];
  const float* off_w = (const float*)d_in[15]; const float* off_b = (const float*)d_in[16];
  const float* aw_w  = (const float*)d_in[17]; const float* aw_b  = (const float*)d_in[18];
  const float* val_w = (const float*)d_in[19]; const float* val_b = (const float*)d_in[20];
  const float* co_w  = (const float*)d_in[21]; const float* co_b  = (const float*)d_in[22];
  const float* n2g = (const float*)d_in[23]; const float* n2b = (const float*)d_in[24];
  const float* ff1_w = (const float*)d_in[25]; const float* ff1_b = (const float*)d_in[26];
  const float* ff2_w = (const float*)d_in[27]; const float* ff2_b = (const float*)d_in[28];
  const float* n3g = (const float*)d_in[29]; const float* n3b = (const float*)d_in[30];

  char* ws = (char*)d_ws;
  size_t NE = (size_t)NROWS * D_;
  __hip_bfloat16* Vv = (__hip_bfloat16*)ws;     // value bf16 (89 MB)
  __hip_bfloat16* FFM = (__hip_bfloat16*)ws;    // ffn hidden bf16 overlays
  size_t p = (size_t)B_ * S_ * D_ * sizeof(__hip_bfloat16);
  float* A  = (float*)(ws + p); p += NE*4;      // rope out
  float* Qb = (float*)(ws + p); p += NE*4;      // q bf16 / off fp32
  float* Kb = (float*)(ws + p); p += NE*4;      // k bf16 / aw fp32 (first half); Wt in tail
  float* Vh = (float*)(ws + p); p += NE*4;      // Vt bf16 (attn V transposed)
  float* S1 = (float*)(ws + p); p += NE*4;      // attn out / sampled
  float* S2 = (float*)(ws + p); p += NE*4;      // proj out
  float* T1 = (float*)(ws + p); p += NE*4;      // tgt1 / tgt2
  short* Wt = (short*)((char*)Kb + NE*2);       // 3.08 MB in free tail of Kb
  float* out = (float*)d_out;
  (void)ws_size; (void)in_sizes; (void)n_in; (void)out_size;

  const short* qk_t  = Wt;                 // [512][256]: wq rows 0..255, wk 256..511
  const short* wv_t  = Wt + 131072;
  const short* sa_t  = Wt + 196608;
  const short* offaw_t = Wt + 262144;      // [384][256]: off rows 0..255, aw 256..383
  const short* val_t = Wt + 360448;
  const short* co_t  = Wt + 425984;
  const short* ff1_t = Wt + 491520;
  const short* ff2_t = Wt + 1015808;

  wtrans_kernel<<<1504, 256, 0, stream>>>(wq, wk, wv, sa_wo, off_w, val_w,
                                          co_w, aw_w, ff1_w, ff2_w, Wt);

  // self-attention branch
  rope_kernel<<<NROWS, 128, 0, stream>>>(tgt, qpos, boxes, A);
  mgemm_kernel<32,256,false,false,false,3><<<dim3(225,2), 256, 0, stream>>>(
      A, nullptr, qk_t, bq, bk, Qb, Kb, NROWS, 512);
  mgemm_kernel<32,256,false,false,false,2><<<dim3(225,1), 256, 0, stream>>>(
      tgt, nullptr, wv_t, bv, nullptr, Vh, nullptr, NROWS, 256);
  mfma_attn_kernel<<<57 * B_ * H_, 64, 0, stream>>>(
      (const __hip_bfloat16*)Qb, (const __hip_bfloat16*)Kb,
      (const __hip_bfloat16*)Vh, S1);
  mgemm_kernel<32,256,false,false,false,0><<<dim3(225,1), 256, 0, stream>>>(
      S1, nullptr, sa_t, sa_bo, nullptr, S2, nullptr, NROWS, 256);
  add_ln_kernel<<<NROWS, 256, 0, stream>>>(tgt, S2, n1g, n1b, T1);

  // cross-attention branch
  mgemm_kernel<64,256,false,false,false,1><<<dim3(2720,1), 256, 0, stream>>>(
      memory, nullptr, val_t, val_b, nullptr, Vv, nullptr, B_*S_, 256);
  mgemm_kernel<32,256,false,true,false,4><<<dim3(225,2), 256, 0, stream>>>(
      T1, qpos, offaw_t, off_b, aw_b, Qb, Kb, NROWS, 384);
  sample_kernel<<<NROWS, 256, 0, stream>>>(Vv, Qb, Kb, refp, S1);
  mgemm_kernel<32,256,false,false,false,0><<<dim3(225,1), 256, 0, stream>>>(
      S1, nullptr, co_t, co_b, nullptr, S2, nullptr, NROWS, 256);
  add_ln_kernel<<<NROWS, 256, 0, stream>>>(T1, S2, n2g, n2b, T1);

  // ffn
  mgemm_kernel<32,256,false,false,true,1><<<dim3(225,8), 256, 0, stream>>>(
      T1, nullptr, ff1_t, ff1_b, nullptr, FFM, nullptr, NROWS, FF_);
  mgemm_kernel<32,2048,true,false,false,0><<<dim3(225,1), 256, 0, stream>>>(
      FFM, nullptr, ff2_t, ff2_b, nullptr, S2, nullptr, NROWS, 256);
  add_ln_kernel<<<NROWS, 256, 0, stream>>>(T1, S2, n3g, n3b, out);
}